// Round 3
// baseline (65.231 us; speedup 1.0000x reference)
//
#include <hip/hip_runtime.h>

#ifndef FLT_MAX
#define FLT_MAX 3.402823466e+38f
#endif

__device__ __forceinline__ float sel3(int i, float a, float b, float c) {
    return i == 0 ? a : (i == 1 ? b : c);
}

// One 64-lane wave per edge; 4 edges per 256-thread block.
// x2 staged in LDS as SoA [wave][component][64] so the j-scan reads are
// 3x ds_read_b128 per 4 columns at compile-time immediate offsets
// (uniform-address broadcast -> conflict-free, zero address VALU).
__global__ __launch_bounds__(256) void clustgeo_edge_kernel(
    const float* __restrict__ data,    // (N,4) f32; coords = cols 1..3
    const int*   __restrict__ clusts,  // (C,64) int (harness-converted from i64)
    const int*   __restrict__ eidx,    // (2,E)  int
    float*       __restrict__ out,     // (E,19) f32
    int E)
{
    const int wave = threadIdx.x >> 6;
    const int lane = threadIdx.x & 63;
    const int e = blockIdx.x * 4 + wave;
    if (e >= E) return;

    __shared__ float sx2[4][3][64];   // 3 KiB; per-wave private slice

    const int a = eidx[e];
    const int b = eidx[E + e];
    const int p1 = clusts[a * 64 + lane];
    const int p2 = clusts[b * 64 + lane];
    const float4 r1 = *reinterpret_cast<const float4*>(data + (size_t)p1 * 4);
    const float4 r2 = *reinterpret_cast<const float4*>(data + (size_t)p2 * 4);
    const float x1x = r1.y, x1y = r1.z, x1z = r1.w;
    sx2[wave][0][lane] = r2.y;
    sx2[wave][1][lane] = r2.z;
    sx2[wave][2][lane] = r2.w;
    // No __syncthreads(): each wave reads only its own slice; same-wave
    // LDS RAW is ordered by compiler-inserted lgkmcnt waits.

    const float4* rx = reinterpret_cast<const float4*>(&sx2[wave][0][0]);
    const float4* ry = reinterpret_cast<const float4*>(&sx2[wave][1][0]);
    const float4* rz = reinterpret_cast<const float4*>(&sx2[wave][2][0]);

    // Strict < keeps the FIRST minimum per lane (numpy argmin). __f*_rn pins
    // exact f32 mul/add order (no FMA contraction) so near-ties resolve
    // identically to the numpy reference.
    float best = FLT_MAX;
    int bj = 0;
    #pragma unroll
    for (int g = 0; g < 16; ++g) {
        const float4 X = rx[g];
        const float4 Y = ry[g];
        const float4 Z = rz[g];
        #pragma unroll
        for (int u = 0; u < 4; ++u) {
            const float sx = sel3(u, X.x, X.y, u == 3 ? X.w : X.z);
            const float sy = sel3(u, Y.x, Y.y, u == 3 ? Y.w : Y.z);
            const float sz = sel3(u, Z.x, Z.y, u == 3 ? Z.w : Z.z);
            const float dx = __fsub_rn(x1x, sx);
            const float dy = __fsub_rn(x1y, sy);
            const float dz = __fsub_rn(x1z, sz);
            const float d2 = __fadd_rn(
                __fadd_rn(__fmul_rn(dx, dx), __fmul_rn(dy, dy)),
                __fmul_rn(dz, dz));
            const int j = g * 4 + u;
            if (d2 < best) { best = d2; bj = j; }
        }
    }
    int idx = (lane << 6) | bj;  // flattened i*64+j (i-major, matches reshape)

    // 64-lane butterfly reduce: min value, ties -> lowest flattened index.
    #pragma unroll
    for (int off = 32; off > 0; off >>= 1) {
        const float ov = __shfl_xor(best, off, 64);
        const int   oi = __shfl_xor(idx,  off, 64);
        if (ov < best || (ov == best && oi < idx)) { best = ov; idx = oi; }
    }

    const int i1 = idx >> 6;   // uniform across the wave after the butterfly
    const int i2 = idx & 63;
    const float v1x = __shfl(x1x, i1, 64);
    const float v1y = __shfl(x1y, i1, 64);
    const float v1z = __shfl(x1z, i1, 64);
    const float v2x = sx2[wave][0][i2];
    const float v2y = sx2[wave][1][i2];
    const float v2z = sx2[wave][2][i2];

    float dx = v1x - v2x, dy = v1y - v2y, dz = v1z - v2z;
    const float lend = sqrtf(dx * dx + dy * dy + dz * dz);
    if (lend > 0.f) { dx /= lend; dy /= lend; dz /= lend; }

    if (lane < 19) {
        float o;
        if (lane < 3)       o = sel3(lane,     v1x, v1y, v1z);
        else if (lane < 6)  o = sel3(lane - 3, v2x, v2y, v2z);
        else if (lane < 9)  o = sel3(lane - 6, dx, dy, dz);
        else if (lane == 9) o = lend;
        else {
            const int k = lane - 10;
            o = sel3(k / 3, dx, dy, dz) * sel3(k % 3, dx, dy, dz);
        }
        out[(size_t)e * 19 + lane] = o;
    }
}

extern "C" void kernel_launch(void* const* d_in, const int* in_sizes, int n_in,
                              void* d_out, int out_size, void* d_ws, size_t ws_size,
                              hipStream_t stream) {
    const float* data   = (const float*)d_in[0];
    const int*   clusts = (const int*)d_in[1];
    const int*   eidx   = (const int*)d_in[2];
    float*       out    = (float*)d_out;
    const int E = in_sizes[2] / 2;           // edge_index is (2, E)
    const int blocks = (E + 3) / 4;          // 4 edges (waves) per block
    clustgeo_edge_kernel<<<blocks, 256, 0, stream>>>(data, clusts, eidx, out, E);
}

// Round 4
// 46.915 us; speedup vs baseline: 1.3904x; 1.3904x over previous
//
#include <hip/hip_runtime.h>

#ifndef FLT_MAX
#define FLT_MAX 3.402823466e+38f
#endif

__device__ __forceinline__ float getc(const float4& v, int u) {
    return u == 0 ? v.x : (u == 1 ? v.y : (u == 2 ? v.z : v.w));
}

__device__ __forceinline__ float sel3(int i, float a, float b, float c) {
    return i == 0 ? a : (i == 1 ? b : c);
}

// One 64-lane wave per edge; 4 edges per 256-thread block.
// x2 staged in LDS SoA [wave][comp][64]; the j-scan reads 3x ds_read_b128
// per 4 columns (uniform-address broadcast, conflict-free), software-
// pipelined one group ahead with a rolling register buffer so the LDS
// latency hides under the current group's 44 VALU ops. launch_bounds
// (256,8) pins VGPR<=64 so 8 waves/SIMD stay resident.
__global__ __launch_bounds__(256, 8) void clustgeo_edge_kernel(
    const float* __restrict__ data,    // (N,4) f32; coords = cols 1..3
    const int*   __restrict__ clusts,  // (C,64) int (harness-converted from i64)
    const int*   __restrict__ eidx,    // (2,E)  int
    float*       __restrict__ out,     // (E,19) f32
    int E)
{
    const int wave = threadIdx.x >> 6;
    const int lane = threadIdx.x & 63;
    const int e = blockIdx.x * 4 + wave;
    if (e >= E) return;

    __shared__ float sx2[4][3][64];   // 3 KiB; per-wave private slice

    const int a = eidx[e];
    const int b = eidx[E + e];
    const int p1 = clusts[a * 64 + lane];
    const int p2 = clusts[b * 64 + lane];
    const float4 r1 = *reinterpret_cast<const float4*>(data + (size_t)p1 * 4);
    const float4 r2 = *reinterpret_cast<const float4*>(data + (size_t)p2 * 4);
    const float x1x = r1.y, x1y = r1.z, x1z = r1.w;
    const float x2x = r2.y, x2y = r2.z, x2z = r2.w;
    sx2[wave][0][lane] = x2x;
    sx2[wave][1][lane] = x2y;
    sx2[wave][2][lane] = x2z;
    // No __syncthreads(): each wave reads only its own slice; same-wave
    // LDS RAW is ordered by compiler-inserted lgkmcnt waits (validated R3).

    const float4* rx = reinterpret_cast<const float4*>(&sx2[wave][0][0]);
    const float4* ry = reinterpret_cast<const float4*>(&sx2[wave][1][0]);
    const float4* rz = reinterpret_cast<const float4*>(&sx2[wave][2][0]);

    // Strict < keeps the FIRST minimum per lane (numpy argmin). __f*_rn pins
    // exact f32 mul/add order (no FMA) so ties resolve identically to numpy.
    float best = FLT_MAX;
    int bj = 0;

#define COMP4(G, CX, CY, CZ)                                                   \
    _Pragma("unroll")                                                          \
    for (int u = 0; u < 4; ++u) {                                              \
        const float dx = __fsub_rn(x1x, getc(CX, u));                          \
        const float dy = __fsub_rn(x1y, getc(CY, u));                          \
        const float dz = __fsub_rn(x1z, getc(CZ, u));                          \
        const float d2 = __fadd_rn(                                            \
            __fadd_rn(__fmul_rn(dx, dx), __fmul_rn(dy, dy)),                   \
            __fmul_rn(dz, dz));                                                \
        const int j = (G) * 4 + u;                                             \
        if (d2 < best) { best = d2; bj = j; }                                  \
    }

    float4 cX = rx[0], cY = ry[0], cZ = rz[0];
    #pragma unroll 3
    for (int g = 0; g < 15; ++g) {
        const float4 nX = rx[g + 1];   // prefetch next group (rolling buffer)
        const float4 nY = ry[g + 1];
        const float4 nZ = rz[g + 1];
        COMP4(g, cX, cY, cZ);
        cX = nX; cY = nY; cZ = nZ;
    }
    COMP4(15, cX, cY, cZ);
#undef COMP4

    // Wave argmin: min value via swizzle butterfly, then first winning lane.
    // Lowest lane among equal-to-min = lowest i = lowest flattened index
    // (per-lane bj is already the first j achieving that lane's min).
    float bm = best;
    #pragma unroll
    for (int off = 32; off; off >>= 1) bm = fminf(bm, __shfl_xor(bm, off, 64));
    const unsigned long long msk = __ballot(best == bm);
    const int i1 = (int)__ffsll((unsigned long long)msk) - 1;
    const int i2 = __builtin_amdgcn_readlane(bj, i1);

    const float v1x = __uint_as_float(__builtin_amdgcn_readlane(__float_as_uint(x1x), i1));
    const float v1y = __uint_as_float(__builtin_amdgcn_readlane(__float_as_uint(x1y), i1));
    const float v1z = __uint_as_float(__builtin_amdgcn_readlane(__float_as_uint(x1z), i1));
    const float v2x = __uint_as_float(__builtin_amdgcn_readlane(__float_as_uint(x2x), i2));
    const float v2y = __uint_as_float(__builtin_amdgcn_readlane(__float_as_uint(x2y), i2));
    const float v2z = __uint_as_float(__builtin_amdgcn_readlane(__float_as_uint(x2z), i2));

    float dx = v1x - v2x, dy = v1y - v2y, dz = v1z - v2z;
    const float lend = sqrtf(dx * dx + dy * dy + dz * dz);
    if (lend > 0.f) { dx /= lend; dy /= lend; dz /= lend; }

    if (lane < 19) {
        float o;
        if (lane < 3)       o = sel3(lane,     v1x, v1y, v1z);
        else if (lane < 6)  o = sel3(lane - 3, v2x, v2y, v2z);
        else if (lane < 9)  o = sel3(lane - 6, dx, dy, dz);
        else if (lane == 9) o = lend;
        else {
            const int k = lane - 10;
            o = sel3(k / 3, dx, dy, dz) * sel3(k % 3, dx, dy, dz);
        }
        out[(size_t)e * 19 + lane] = o;
    }
}

extern "C" void kernel_launch(void* const* d_in, const int* in_sizes, int n_in,
                              void* d_out, int out_size, void* d_ws, size_t ws_size,
                              hipStream_t stream) {
    const float* data   = (const float*)d_in[0];
    const int*   clusts = (const int*)d_in[1];
    const int*   eidx   = (const int*)d_in[2];
    float*       out    = (float*)d_out;
    const int E = in_sizes[2] / 2;           // edge_index is (2, E)
    const int blocks = (E + 3) / 4;          // 4 edges (waves) per block
    clustgeo_edge_kernel<<<blocks, 256, 0, stream>>>(data, clusts, eidx, out, E);
}

// Round 5
// 33.713 us; speedup vs baseline: 1.9349x; 1.3916x over previous
//
#include <hip/hip_runtime.h>

#ifndef FLT_MAX
#define FLT_MAX 3.402823466e+38f
#endif

__device__ __forceinline__ float rlanef(float v, int j) {
    return __uint_as_float(__builtin_amdgcn_readlane(__float_as_uint(v), j));
}

__device__ __forceinline__ float sel3(int i, float a, float b, float c) {
    return i == 0 ? a : (i == 1 ? b : c);
}

// Deterministic d2: explicit sub/mul/fma, used identically in BOTH the scan
// pass and the reconstruction pass so recomputed values are bit-identical.
__device__ __forceinline__ float d2f(float ax, float ay, float az,
                                     float bx, float by, float bz) {
    const float dx = __fsub_rn(ax, bx);
    const float dy = __fsub_rn(ay, by);
    const float dz = __fsub_rn(az, bz);
    return __builtin_fmaf(dx, dx, __builtin_fmaf(dy, dy, __fmul_rn(dz, dz)));
}

// One 64-lane wave per edge; 4 edges per 256-thread block.
// Phase 1: value-only min scan (7 VALU/pair: 3 sub, 1 mul, 2 fma, 1 min),
//          x2 broadcast from LDS SoA via ds_read_b128 at immediate offsets.
// Wave argmin: lowest lane whose row-min equals the wave min = lowest i.
// Phase 2: one parallel recompute of row i1 (lane j holds x2[j] in regs),
//          ballot+ffs gives the first j — exact numpy argmin semantics.
__global__ __launch_bounds__(256, 8) void clustgeo_edge_kernel(
    const float* __restrict__ data,    // (N,4) f32; coords = cols 1..3
    const int*   __restrict__ clusts,  // (C,64) int (harness-converted from i64)
    const int*   __restrict__ eidx,    // (2,E)  int
    float*       __restrict__ out,     // (E,19) f32
    int E)
{
    const int wave = threadIdx.x >> 6;
    const int lane = threadIdx.x & 63;
    const int e = blockIdx.x * 4 + wave;
    if (e >= E) return;

    __shared__ float sx2[4][3][64];   // 3 KiB; per-wave private slice

    const int a = eidx[e];
    const int b = eidx[E + e];
    const int p1 = clusts[a * 64 + lane];
    const int p2 = clusts[b * 64 + lane];
    const float4 r1 = *reinterpret_cast<const float4*>(data + (size_t)p1 * 4);
    const float4 r2 = *reinterpret_cast<const float4*>(data + (size_t)p2 * 4);
    const float x1x = r1.y, x1y = r1.z, x1z = r1.w;
    const float x2x = r2.y, x2y = r2.z, x2z = r2.w;
    sx2[wave][0][lane] = x2x;
    sx2[wave][1][lane] = x2y;
    sx2[wave][2][lane] = x2z;
    // No __syncthreads(): each wave reads only its own slice; same-wave LDS
    // RAW is ordered by compiler-inserted lgkmcnt waits (validated R3/R4).

    const float4* rx = reinterpret_cast<const float4*>(&sx2[wave][0][0]);
    const float4* ry = reinterpret_cast<const float4*>(&sx2[wave][1][0]);
    const float4* rz = reinterpret_cast<const float4*>(&sx2[wave][2][0]);

    // Phase 1: per-lane row minimum, value only. 4 accumulators break the
    // fmin dependence chain; min is order-independent for values.
    float b0 = FLT_MAX, b1 = FLT_MAX, b2 = FLT_MAX, b3 = FLT_MAX;
    #pragma unroll 4
    for (int g = 0; g < 16; ++g) {
        const float4 X = rx[g];
        const float4 Y = ry[g];
        const float4 Z = rz[g];
        b0 = fminf(b0, d2f(x1x, x1y, x1z, X.x, Y.x, Z.x));
        b1 = fminf(b1, d2f(x1x, x1y, x1z, X.y, Y.y, Z.y));
        b2 = fminf(b2, d2f(x1x, x1y, x1z, X.z, Y.z, Z.z));
        b3 = fminf(b3, d2f(x1x, x1y, x1z, X.w, Y.w, Z.w));
    }
    const float rowmin = fminf(fminf(b0, b1), fminf(b2, b3));

    // Wave minimum of rowmin.
    float bm = rowmin;
    #pragma unroll
    for (int off = 32; off; off >>= 1) bm = fminf(bm, __shfl_xor(bm, off, 64));

    // Lowest lane whose row attains bm == lowest i (numpy row-major first).
    const unsigned long long mi = __ballot(rowmin == bm);
    const int i1 = (int)__ffsll(mi) - 1;

    // Phase 2: recompute row i1 across lanes (lane j owns x2[j] in regs).
    // d2f is bit-identical to phase 1, so the first-match j is exact.
    const float v1x = rlanef(x1x, i1);
    const float v1y = rlanef(x1y, i1);
    const float v1z = rlanef(x1z, i1);
    const float dj = d2f(v1x, v1y, v1z, x2x, x2y, x2z);
    const unsigned long long mj = __ballot(dj == bm);
    const int i2 = (int)__ffsll(mj) - 1;

    const float v2x = rlanef(x2x, i2);
    const float v2y = rlanef(x2y, i2);
    const float v2z = rlanef(x2z, i2);

    float dx = v1x - v2x, dy = v1y - v2y, dz = v1z - v2z;
    const float lend = sqrtf(dx * dx + dy * dy + dz * dz);
    if (lend > 0.f) { dx /= lend; dy /= lend; dz /= lend; }

    if (lane < 19) {
        float o;
        if (lane < 3)       o = sel3(lane,     v1x, v1y, v1z);
        else if (lane < 6)  o = sel3(lane - 3, v2x, v2y, v2z);
        else if (lane < 9)  o = sel3(lane - 6, dx, dy, dz);
        else if (lane == 9) o = lend;
        else {
            const int k = lane - 10;
            o = sel3(k / 3, dx, dy, dz) * sel3(k % 3, dx, dy, dz);
        }
        out[(size_t)e * 19 + lane] = o;
    }
}

extern "C" void kernel_launch(void* const* d_in, const int* in_sizes, int n_in,
                              void* d_out, int out_size, void* d_ws, size_t ws_size,
                              hipStream_t stream) {
    const float* data   = (const float*)d_in[0];
    const int*   clusts = (const int*)d_in[1];
    const int*   eidx   = (const int*)d_in[2];
    float*       out    = (float*)d_out;
    const int E = in_sizes[2] / 2;           // edge_index is (2, E)
    const int blocks = (E + 3) / 4;          // 4 edges (waves) per block
    clustgeo_edge_kernel<<<blocks, 256, 0, stream>>>(data, clusts, eidx, out, E);
}